// Round 12
// baseline (5446.819 us; speedup 1.0000x reference)
//
#include <hip/hip_runtime.h>

#define T_STEPS 1000
#define DT 0.1f
#define HIDDEN 128
#define N_AGENTS 1024
#define NBLK (T_STEPS / 2)
#define PSLOTS 24

// tanh(x) = 1 - 2/(exp(2x)+1); exact at +/-inf, ~1e-7 rel error.
__device__ __forceinline__ float tanh_fast(float x) {
    float e = __expf(2.0f * x);
    return 1.0f - 2.0f * __builtin_amdgcn_rcpf(e + 1.0f);
}

// Opaque 16B load: asm results can't be remat'd/sunk into the loop
// (R6-R11 proven: weights stay register-file-resident, zero reload traffic).
__device__ __forceinline__ float4 opaque_load16(const float* p) {
    float4 v;
    asm volatile("global_load_dwordx4 %0, %1, off\n\ts_waitcnt vmcnt(0)"
                 : "=v"(v)
                 : "v"((unsigned long long)(uintptr_t)p)
                 : "memory");
    return v;
}

// Wave-uniform float -> SGPR.
__device__ __forceinline__ float uniformf(float v) {
    return __builtin_bit_cast(float,
        __builtin_amdgcn_readfirstlane(__builtin_bit_cast(int, v)));
}

// 64-lane sum on the VALU pipe via DPP row ops (R11-verified).
__device__ __forceinline__ float wave_sum_dpp(float x) {
    float t;
    #define DPPADD(ctrl, rmask)                                              \
        t = __builtin_bit_cast(float, __builtin_amdgcn_update_dpp(           \
                0, __builtin_bit_cast(int, x), ctrl, rmask, 0xf, false));    \
        x += t;
    DPPADD(0x111, 0xf)
    DPPADD(0x112, 0xf)
    DPPADD(0x114, 0xf)
    DPPADD(0x118, 0xf)
    DPPADD(0x142, 0xa)
    DPPADD(0x143, 0xc)
    #undef DPPADD
    return __builtin_bit_cast(float,
        __builtin_amdgcn_readlane(__builtin_bit_cast(int, x), 63));
}

// CONSUMER/PRODUCER PUSH MODEL — no barrier in the serial chain.
//
// R11 post-mortem: wall = 2 passes x 1000 x S, S~1230 cyc because the
// per-step chain crossed 2 barriers + 2 LDS round trips. Here ages are
// split 8/8/8/8 across 4 waves and each lane owns TWO rows (lane,lane+64),
// so ONE wave (role 0 = consumer, rotated by agent&3 to dodge the R10 SIMD
// convoy) holds all 128 rows: it keeps the state in registers and runs
// push->relu->DPP-reduce->tanh->dynamics->conc with NO barrier. Producer
// wave role w covers ages 8w..8w+7; its partial for step s is complete at
// s-8w (>=8 steps early) and is shipped via a 24-slot LDS ring, prefetched
// by the consumer 1 step ahead. One barrier per 2-step block bounds
// producer lag (<=4 steps << 8-step slack); every ship->consume pair is
// barrier-separated (gap >= 4rp-1 >= 3 blocks; slot reuse gap >= 1 block).
__global__ __launch_bounds__(256)
__attribute__((amdgpu_waves_per_eu(3, 4)))
void sim_kernel(const float* __restrict__ target_pos,
                const float* __restrict__ logsigma,
                const float* __restrict__ x_inits,
                const float* W1,
                const float* __restrict__ b1,
                const float* __restrict__ W2,
                const float* __restrict__ b2,
                float2* __restrict__ ws) {
    const int agent = blockIdx.x;
    const int tid  = threadIdx.x;   // 0..255
    const int wave = tid >> 6;      // 0..3
    const int lane = tid & 63;
    const int rp   = (wave - (agent & 3)) & 3;  // role: 0=consumer, 1..3=prod

    __shared__ float2 part[3][PSLOTS][64];  // producer partial rings
    __shared__ float4 e4ring[8];            // state history ring

    const float tx0 = uniformf(target_pos[0]), ty0 = uniformf(target_pos[1]);
    const float tx1 = uniformf(target_pos[2]), ty1 = uniformf(target_pos[3]);
    const float tx2 = uniformf(target_pos[4]), ty2 = uniformf(target_pos[5]);
    const float is0 = uniformf(1.0f / expf(logsigma[0]));
    const float is1 = uniformf(1.0f / expf(logsigma[1]));
    const float is2 = uniformf(1.0f / expf(logsigma[2]));

    // Weights for rows lane (A) and lane+64 (B), ages 8rp..8rp+7:
    // pos cols 24rp..24rp+23, conc cols 96+8rp..96+8rp+7. 64 floats/lane.
    float WpA[24], WcA[8], WpB[24], WcB[8];
    {
        const float* rA = W1 + lane * 128 + 24 * rp;
        const float* rB = W1 + (lane + 64) * 128 + 24 * rp;
        #pragma unroll
        for (int i = 0; i < 6; ++i) {
            float4 v = opaque_load16(rA + 4 * i);
            WpA[4*i]=v.x; WpA[4*i+1]=v.y; WpA[4*i+2]=v.z; WpA[4*i+3]=v.w;
            float4 u = opaque_load16(rB + 4 * i);
            WpB[4*i]=u.x; WpB[4*i+1]=u.y; WpB[4*i+2]=u.z; WpB[4*i+3]=u.w;
        }
        const float* cA = W1 + lane * 128 + 96 + 8 * rp;
        const float* cB = W1 + (lane + 64) * 128 + 96 + 8 * rp;
        #pragma unroll
        for (int i = 0; i < 2; ++i) {
            float4 v = opaque_load16(cA + 4 * i);
            WcA[4*i]=v.x; WcA[4*i+1]=v.y; WcA[4*i+2]=v.z; WcA[4*i+3]=v.w;
            float4 u = opaque_load16(cB + 4 * i);
            WcB[4*i]=u.x; WcB[4*i+1]=u.y; WcB[4*i+2]=u.z; WcB[4*i+3]=u.w;
        }
    }
    const float b1a  = b1[lane],        b1b  = b1[lane + 64];
    const float w20a = W2[lane],        w20b = W2[lane + 64];
    const float w21a = W2[HIDDEN+lane], w21b = W2[HIDDEN+lane+64];
    const float b2x = uniformf(b2[0]), b2y = uniformf(b2[1]);

    auto conc = [&](float px, float py) {
        float dx0 = px - tx0, dy0 = py - ty0;
        float dx1 = px - tx1, dy1 = py - ty1;
        float dx2 = px - tx2, dy2 = py - ty2;
        float cc  = is0 * __expf(-(dx0*dx0 + dy0*dy0) * is0);
        cc       += is1 * __expf(-(dx1*dx1 + dy1*dy1) * is1);
        cc       += is2 * __expf(-(dx2*dx2 + dy2*dy2) * is2);
        return cc;
    };

    float x  = uniformf(x_inits[3 * agent]);
    float y  = uniformf(x_inits[3 * agent + 1]);
    float th = uniformf(x_inits[3 * agent + 2]);
    float c  = conc(x, y);

    // Ring seed (virtual pushes of e(0)); producers shifted +2 because they
    // skip block 0 but the rotation still runs.
    float RA[10], RB[10];
    #pragma unroll
    for (int i = 0; i < 10; ++i) { RA[i] = 0.f; RB[i] = 0.f; }
    float S0a, S0b;
    {
        const int sh = (rp == 0) ? 0 : 2;
        float aA = 0.f, aB = 0.f;
        #pragma unroll
        for (int k = 7; k >= 1; --k) {
            aA += WpA[3*k]*x + WpA[3*k+1]*y + WpA[3*k+2]*th + WcA[k]*c;
            aB += WpB[3*k]*x + WpB[3*k+1]*y + WpB[3*k+2]*th + WcB[k]*c;
            RA[k-1+sh] = aA; RB[k-1+sh] = aB;
        }
        S0a = aA + WpA[0]*x + WpA[1]*y + WpA[2]*th + WcA[0]*c;
        S0b = aB + WpB[0]*x + WpB[1]*y + WpB[2]*th + WcB[0]*c;
    }

    // Prefill: sigma < 8rp is all-e(0) = full 8-age sum.
    if (rp >= 1) {
        for (int s = 0; s < 8 * rp; ++s)
            part[rp-1][s][lane] = make_float2(S0a, S0b);
    } else if (lane == 0) {
        e4ring[0] = make_float4(x, y, th, c);
    }
    __syncthreads();

    float2 pf1, pf2, pf3;
    if (rp == 0) {   // pre-read partials for step 0
        pf1 = part[0][0][lane];
        pf2 = part[1][0][lane];
        pf3 = part[2][0][lane];
    }
    int pfidx = 1;                   // next consumer prefetch slot
    int sidx  = (8 * rp) % PSLOTS;   // producer's first natural ship slot
    float S_c = 0.f, S_u = 0.f;

    #pragma unroll 1
    for (int tt = 0; tt < NBLK; ++tt) {
        __syncthreads();   // ONE barrier per 2 steps (not in serial chain)
        if (rp == 0) {
            #pragma unroll
            for (int j = 0; j < 2; ++j) {
                const int t = 2 * tt + j;
                // push e(t) into own 8 ages (k=0 completes h_pre(t))
                #pragma unroll
                for (int k = 0; k < 8; ++k) {
                    RA[j+k] = fmaf(WpA[3*k], x, fmaf(WpA[3*k+1], y,
                              fmaf(WpA[3*k+2], th, fmaf(WcA[k], c, RA[j+k]))));
                    RB[j+k] = fmaf(WpB[3*k], x, fmaf(WpB[3*k+1], y,
                              fmaf(WpB[3*k+2], th, fmaf(WcB[k], c, RB[j+k]))));
                }
                float ha = fmaxf(RA[j] + ((pf1.x + pf2.x) + (pf3.x + b1a)), 0.f);
                float hb = fmaxf(RB[j] + ((pf1.y + pf2.y) + (pf3.y + b1b)), 0.f);
                // prefetch next step's partials (latency hidden under push)
                float2 npf1 = part[0][pfidx][lane];
                float2 npf2 = part[1][pfidx][lane];
                float2 npf3 = part[2][pfidx][lane];
                pfidx = (pfidx == PSLOTS - 1) ? 0 : pfidx + 1;
                // layer 2 over all 128 rows, in-wave
                float P0 = wave_sum_dpp(fmaf(w20a, ha, w20b * hb));
                float P1 = wave_sum_dpp(fmaf(w21a, ha, w21b * hb));
                float v  = tanh_fast(P0 + b2x);
                float wv = tanh_fast(P1 + b2y);
                S_u += v * v + wv * wv;
                float sn = __sinf(th), cs = __cosf(th);
                float dv = DT * v;
                x  = fmaf(dv, cs, x);
                y  = fmaf(dv, sn, y);
                th = fmaf(DT, wv, th);
                c  = conc(x, y);
                S_c += c;
                if (lane == 0) e4ring[(t + 1) & 7] = make_float4(x, y, th, c);
                pf1 = npf1; pf2 = npf2; pf3 = npf3;
            }
        } else {
            #pragma unroll
            for (int j = 0; j < 2; ++j) {
                const int tau = 2 * tt - 2 + j;   // state from block tt-1
                if (tau >= 0) {
                    float4 e = e4ring[tau & 7];
                    #pragma unroll
                    for (int k = 0; k < 8; ++k) {
                        RA[j+k] = fmaf(WpA[3*k], e.x, fmaf(WpA[3*k+1], e.y,
                                  fmaf(WpA[3*k+2], e.z, fmaf(WcA[k], e.w, RA[j+k]))));
                        RB[j+k] = fmaf(WpB[3*k], e.x, fmaf(WpB[3*k+1], e.y,
                                  fmaf(WpB[3*k+2], e.z, fmaf(WcB[k], e.w, RB[j+k]))));
                    }
                    // partial for sigma = tau + 8rp is now complete -> ship
                    part[rp-1][sidx][lane] = make_float2(RA[j], RB[j]);
                    sidx = (sidx == PSLOTS - 1) ? 0 : sidx + 1;
                }
            }
        }
        // rotate pending rings by 2 (shipped/consumed slots fall off)
        #pragma unroll
        for (int i = 0; i < 8; ++i) { RA[i] = RA[i+2]; RB[i] = RB[i+2]; }
        RA[8] = RA[9] = RB[8] = RB[9] = 0.f;
    }

    if (rp == 0 && lane == 0) ws[agent] = make_float2(S_c, S_u);
}

__global__ void reduce_kernel(const float2* __restrict__ ws,
                              float* __restrict__ out) {
    const int tid = threadIdx.x;  // 256 threads
    float sc = 0.f, su = 0.f;
    for (int i = tid; i < N_AGENTS; i += 256) {
        float2 v = ws[i];
        sc += v.x;
        su += v.y;
    }
    #pragma unroll
    for (int off = 32; off > 0; off >>= 1) {
        sc += __shfl_xor(sc, off);
        su += __shfl_xor(su, off);
    }
    __shared__ float2 partw[4];
    int wave = tid >> 6;
    if ((tid & 63) == 0) partw[wave] = make_float2(sc, su);
    __syncthreads();
    if (tid == 0) {
        float SC = partw[0].x + partw[1].x + partw[2].x + partw[3].x;
        float SU = partw[0].y + partw[1].y + partw[2].y + partw[3].y;
        const float invNT  = 1.0f / (float)(N_AGENTS * T_STEPS);
        const float invNT2 = 1.0f / (float)(N_AGENTS * T_STEPS * 2);
        out[0] = -SC * invNT + SU * invNT2;
    }
}

extern "C" void kernel_launch(void* const* d_in, const int* in_sizes, int n_in,
                              void* d_out, int out_size, void* d_ws, size_t ws_size,
                              hipStream_t stream) {
    const float* target_pos = (const float*)d_in[0];
    const float* logsigma   = (const float*)d_in[1];
    const float* x_inits    = (const float*)d_in[2];
    const float* W1         = (const float*)d_in[3];
    const float* b1         = (const float*)d_in[4];
    const float* W2         = (const float*)d_in[5];
    const float* b2         = (const float*)d_in[6];
    float2* ws = (float2*)d_ws;

    sim_kernel<<<N_AGENTS, 256, 0, stream>>>(target_pos, logsigma, x_inits,
                                             W1, b1, W2, b2, ws);
    reduce_kernel<<<1, 256, 0, stream>>>(ws, (float*)d_out);
}

// Round 13
// 1010.914 us; speedup vs baseline: 5.3880x; 5.3880x over previous
//
#include <hip/hip_runtime.h>

#define T_STEPS 1000
#define DT 0.1f
#define HIDDEN 128
#define N_AGENTS 1024
#define U 2
#define RING (U + 16)   // pending-accumulator slots

// tanh(x) = 1 - 2/(exp(2x)+1); exact at +/-inf, ~1e-7 rel error.
__device__ __forceinline__ float tanh_fast(float x) {
    float e = __expf(2.0f * x);
    return 1.0f - 2.0f * __builtin_amdgcn_rcpf(e + 1.0f);
}

// Opaque 16B load: asm results can't be remat'd/sunk into the loop
// (R6-R11 proven: weights stay register-file-resident, zero reload traffic).
__device__ __forceinline__ float4 opaque_load16(const float* p) {
    float4 v;
    asm volatile("global_load_dwordx4 %0, %1, off\n\ts_waitcnt vmcnt(0)"
                 : "=v"(v)
                 : "v"((unsigned long long)(uintptr_t)p)
                 : "memory");
    return v;
}

// Wave-uniform float -> SGPR.
__device__ __forceinline__ float uniformf(float v) {
    return __builtin_bit_cast(float,
        __builtin_amdgcn_readfirstlane(__builtin_bit_cast(int, v)));
}

// 64-lane sum on the VALU pipe via DPP row ops (R11-verified, absmax 0.0):
// ~60 cyc latency vs ~240 for a 6-deep ds-pipe shfl chain.
__device__ __forceinline__ float wave_sum_dpp(float x) {
    float t;
    #define DPPADD(ctrl, rmask)                                              \
        t = __builtin_bit_cast(float, __builtin_amdgcn_update_dpp(           \
                0, __builtin_bit_cast(int, x), ctrl, rmask, 0xf, false));    \
        x += t;
    DPPADD(0x111, 0xf)   // row_shr:1
    DPPADD(0x112, 0xf)   // row_shr:2
    DPPADD(0x114, 0xf)   // row_shr:4
    DPPADD(0x118, 0xf)   // row_shr:8
    DPPADD(0x142, 0xa)   // row_bcast15
    DPPADD(0x143, 0xc)   // row_bcast31; lane63 = full sum
    #undef DPPADD
    return __builtin_bit_cast(float,
        __builtin_amdgcn_readlane(__builtin_bit_cast(int, x), 63));
}

// PUSH MODEL, R9 skeleton (ONE barrier/step, redundant tail, per-lane
// state — no owner convoy, no e4buf hop) + R11's two verified wins:
// DPP layer-2 reduction and part1 prefetch (slot written >=15 barriers
// earlier -> race-free; takes the ds_read off the serial chain).
//
// Wave (r,h): lane owns row 64r+lane, ages 16h..16h+15 (64 opaque-pinned
// weight floats/lane + ~40 loop-carried arch VGPRs = the proven no-spill
// envelope at waves_per_eu(3,4); R8/R12 both spilled when exceeding it).
__global__ __launch_bounds__(256)
__attribute__((amdgpu_waves_per_eu(3, 4)))
void sim_kernel(const float* __restrict__ target_pos,
                const float* __restrict__ logsigma,
                const float* __restrict__ x_inits,
                const float* W1,
                const float* __restrict__ b1,
                const float* __restrict__ W2,
                const float* __restrict__ b2,
                float2* __restrict__ ws) {
    const int agent = blockIdx.x;
    const int tid  = threadIdx.x;   // 0..255
    const int wave = tid >> 6;      // 0..3
    const int lane = tid & 63;
    const int r    = wave >> 1;     // row-group: rows 64r+lane
    const int h    = wave & 1;      // age-half: ages 16h..16h+15
    const int row  = (r << 6) + lane;

    __shared__ float part1[2][32][64];          // h=1 -> h=0, 16-step delay
    __shared__ alignas(16) float2 pbf2[2][2];   // [parity][r] = (P0r, P1r)

    const float tx0 = uniformf(target_pos[0]), ty0 = uniformf(target_pos[1]);
    const float tx1 = uniformf(target_pos[2]), ty1 = uniformf(target_pos[3]);
    const float tx2 = uniformf(target_pos[4]), ty2 = uniformf(target_pos[5]);
    const float is0 = uniformf(1.0f / expf(logsigma[0]));
    const float is1 = uniformf(1.0f / expf(logsigma[1]));
    const float is2 = uniformf(1.0f / expf(logsigma[2]));

    // 48 position + 16 conc weights for (row, ages 16h..16h+15).
    float Wp[48], Wc[16];
    {
        const float* rowp = W1 + row * 128;
        #pragma unroll
        for (int i = 0; i < 12; ++i) {
            float4 v = opaque_load16(rowp + 48 * h + 4 * i);
            Wp[4*i] = v.x; Wp[4*i+1] = v.y; Wp[4*i+2] = v.z; Wp[4*i+3] = v.w;
        }
        #pragma unroll
        for (int i = 0; i < 4; ++i) {
            float4 v = opaque_load16(rowp + 96 + 16 * h + 4 * i);
            Wc[4*i] = v.x; Wc[4*i+1] = v.y; Wc[4*i+2] = v.z; Wc[4*i+3] = v.w;
        }
    }
    const float b1r = b1[row];                 // h=0 relu bias
    const float w2a = W2[row];                 // W2 row 0
    const float w2b = W2[HIDDEN + row];        // W2 row 1
    const float b2x = uniformf(b2[0]), b2y = uniformf(b2[1]);

    auto conc = [&](float px, float py) {
        float dx0 = px - tx0, dy0 = py - ty0;
        float dx1 = px - tx1, dy1 = py - ty1;
        float dx2 = px - tx2, dy2 = py - ty2;
        float cc  = is0 * __expf(-(dx0*dx0 + dy0*dy0) * is0);
        cc       += is1 * __expf(-(dx1*dx1 + dy1*dy1) * is1);
        cc       += is2 * __expf(-(dx2*dx2 + dy2*dy2) * is2);
        return cc;
    };

    float x  = uniformf(x_inits[3 * agent]);
    float y  = uniformf(x_inits[3 * agent + 1]);
    float th = uniformf(x_inits[3 * agent + 2]);
    float c  = conc(x, y);

    // Seed pending ring: history pre-filled with e(0).
    // R[k] = sum_{m=k..15} Wloc[m]·e(0)  (slot k <-> step k+16h).
    float R[RING];
    #pragma unroll
    for (int i = 16; i < RING; ++i) R[i] = 0.f;
    {
        float acc = 0.f;
        #pragma unroll
        for (int k = 15; k >= 0; --k) {
            acc = fmaf(Wp[3*k], x,
                   fmaf(Wp[3*k+1], y,
                    fmaf(Wp[3*k+2], th,
                     fmaf(Wc[k], c, acc))));
            R[k] = acc;
        }
    }
    // h=1 partials for steps 0..15 = full e(0) sum = R[0].
    if (h == 1) {
        #pragma unroll
        for (int s = 0; s < 16; ++s) part1[r][s][lane] = R[0];
    }
    __syncthreads();

    float pl = part1[r][0][lane];   // prefetched h=1 partial for step 0
    float S_c = 0.f, S_u = 0.f;
    int t = 0;

    #pragma unroll 1
    for (int tt = 0; tt < T_STEPS / U; ++tt) {
        #pragma unroll
        for (int j = 0; j < U; ++j, ++t) {
            // ---- phase 1: h=0 completes h(t) + layer-2 DPP; h=1 ships ----
            if (h == 0) {
                float hv = fmaxf(R[j] + pl + b1r, 0.f);
                float s0 = wave_sum_dpp(w2a * hv);
                float s1 = wave_sum_dpp(w2b * hv);
                if (lane == 0) pbf2[t & 1][r] = make_float2(s0, s1);
            } else {
                part1[r][(t + 16) & 31][lane] = R[j];
            }
            __syncthreads();   // the ONE barrier per step

            // prefetch next step's h=1 partial (written >=15 barriers ago;
            // latency hidden under the tail + push below)
            pl = part1[r][(t + 1) & 31][lane];

            float4 pa = *(const float4*)&pbf2[t & 1][0];
            float P0 = pa.x + pa.z;
            float P1 = pa.y + pa.w;

            // ---- tail: redundant on all waves (per-lane state, R9-style) ----
            float v  = tanh_fast(P0 + b2x);
            float wv = tanh_fast(P1 + b2y);
            S_u += v * v + wv * wv;

            float sn = __sinf(th), cs = __cosf(th);
            float dv = DT * v;
            x  = fmaf(dv, cs, x);
            y  = fmaf(dv, sn, y);
            th = fmaf(DT, wv, th);

            c = conc(x, y);
            S_c += c;

            // ---- push e(t+1) into pending ring: 64 FMAs ----
            #pragma unroll
            for (int k = 0; k < 16; ++k) {
                R[j+1+k] = fmaf(Wp[3*k], x,
                            fmaf(Wp[3*k+1], y,
                             fmaf(Wp[3*k+2], th,
                              fmaf(Wc[k], c, R[j+1+k]))));
            }
        }
        // ---- rotate pending ring by U ----
        #pragma unroll
        for (int i = 0; i < 16; ++i) R[i] = R[i + U];
        #pragma unroll
        for (int i = 16; i < RING; ++i) R[i] = 0.f;
    }

    if (tid == 0) ws[agent] = make_float2(S_c, S_u);
}

__global__ void reduce_kernel(const float2* __restrict__ ws,
                              float* __restrict__ out) {
    const int tid = threadIdx.x;  // 256 threads
    float sc = 0.f, su = 0.f;
    for (int i = tid; i < N_AGENTS; i += 256) {
        float2 v = ws[i];
        sc += v.x;
        su += v.y;
    }
    #pragma unroll
    for (int off = 32; off > 0; off >>= 1) {
        sc += __shfl_xor(sc, off);
        su += __shfl_xor(su, off);
    }
    __shared__ float2 partw[4];
    int wave = tid >> 6;
    if ((tid & 63) == 0) partw[wave] = make_float2(sc, su);
    __syncthreads();
    if (tid == 0) {
        float SC = partw[0].x + partw[1].x + partw[2].x + partw[3].x;
        float SU = partw[0].y + partw[1].y + partw[2].y + partw[3].y;
        const float invNT  = 1.0f / (float)(N_AGENTS * T_STEPS);
        const float invNT2 = 1.0f / (float)(N_AGENTS * T_STEPS * 2);
        out[0] = -SC * invNT + SU * invNT2;
    }
}

extern "C" void kernel_launch(void* const* d_in, const int* in_sizes, int n_in,
                              void* d_out, int out_size, void* d_ws, size_t ws_size,
                              hipStream_t stream) {
    const float* target_pos = (const float*)d_in[0];
    const float* logsigma   = (const float*)d_in[1];
    const float* x_inits    = (const float*)d_in[2];
    const float* W1         = (const float*)d_in[3];
    const float* b1         = (const float*)d_in[4];
    const float* W2         = (const float*)d_in[5];
    const float* b2         = (const float*)d_in[6];
    float2* ws = (float2*)d_ws;

    sim_kernel<<<N_AGENTS, 256, 0, stream>>>(target_pos, logsigma, x_inits,
                                             W1, b1, W2, b2, ws);
    reduce_kernel<<<1, 256, 0, stream>>>(ws, (float*)d_out);
}

// Round 14
// 992.685 us; speedup vs baseline: 5.4870x; 1.0184x over previous
//
#include <hip/hip_runtime.h>

#define T_STEPS 1000
#define DT 0.1f
#define HIDDEN 128
#define N_AGENTS 1024
#define U 2
#define RING (U + 16)   // pending-accumulator slots (float2 each)

typedef float v2f __attribute__((ext_vector_type(2)));

// tanh(x) = 1 - 2/(exp(2x)+1); exact at +/-inf, ~1e-7 rel error.
__device__ __forceinline__ float tanh_fast(float x) {
    float e = __expf(2.0f * x);
    return 1.0f - 2.0f * __builtin_amdgcn_rcpf(e + 1.0f);
}

// Opaque 8B load: asm output IS the register pair -> cannot be remat'd or
// sunk into the loop (R6-R13 proven residency mechanism), and the pair is
// even-aligned for v_pk_fma_f32 consumption.
__device__ __forceinline__ v2f opaque_load8(const float* p) {
    v2f v;
    asm volatile("global_load_dwordx2 %0, %1, off\n\ts_waitcnt vmcnt(0)"
                 : "=v"(v)
                 : "v"((unsigned long long)(uintptr_t)p)
                 : "memory");
    return v;
}

// Wave-uniform float -> SGPR.
__device__ __forceinline__ float uniformf(float v) {
    return __builtin_bit_cast(float,
        __builtin_amdgcn_readfirstlane(__builtin_bit_cast(int, v)));
}

// 64-lane sum on the VALU pipe via DPP row ops (R11/R13-verified).
__device__ __forceinline__ float wave_sum_dpp(float x) {
    float t;
    #define DPPADD(ctrl, rmask)                                              \
        t = __builtin_bit_cast(float, __builtin_amdgcn_update_dpp(           \
                0, __builtin_bit_cast(int, x), ctrl, rmask, 0xf, false));    \
        x += t;
    DPPADD(0x111, 0xf)   // row_shr:1
    DPPADD(0x112, 0xf)   // row_shr:2
    DPPADD(0x114, 0xf)   // row_shr:4
    DPPADD(0x118, 0xf)   // row_shr:8
    DPPADD(0x142, 0xa)   // row_bcast15
    DPPADD(0x143, 0xc)   // row_bcast31; lane63 = full sum
    #undef DPPADD
    return __builtin_bit_cast(float,
        __builtin_amdgcn_readlane(__builtin_bit_cast(int, x), 63));
}

// Pre-pack W1 into component-paired layout so the sim kernel's weight pairs
// are contiguous 8B loads:
//   pw[row*128 + 2a,2a+1]      = (Wx[a], Wy[a])    a = 0..31
//   pw[row*128 + 64+2a, +1]    = (Wz[a], Wc[a])
__global__ void pack_kernel(const float* __restrict__ W1,
                            float* __restrict__ pw) {
    const int row = blockIdx.x;     // 128
    const int a   = threadIdx.x;    // 32
    const float* rp = W1 + row * 128;
    float* out = pw + row * 128;
    out[2*a]          = rp[3*a];
    out[2*a + 1]      = rp[3*a + 1];
    out[64 + 2*a]     = rp[3*a + 2];
    out[64 + 2*a + 1] = rp[96 + a];
}

// R13 skeleton (ONE barrier/step, redundant tail, DPP layer-2, part1
// prefetch) + PACKED-FP32 push: ring slot = float2 accumulating the
// (x,y)-weighted sum in .lo and the (th,c)-weighted sum in .hi, so each
// age costs 2 v_pk_fma_f32 (gfx950 double-rate fp32) instead of 4 scalar
// v_fma — push issue 128 -> 64 cyc/wave-step, the largest single
// component of R13's ~450 cyc/wave-step VALU issue. Component pairing is
// alignment-stable under the ring's shifting base (age-pairing is not).
//
// Wave (r,h): lane owns row 64r+lane, ages 16h..16h+15 (64 opaque-pinned
// weight floats/lane = proven no-spill envelope at waves_per_eu(3,4)).
__global__ __launch_bounds__(256)
__attribute__((amdgpu_waves_per_eu(3, 4)))
void sim_kernel(const float* __restrict__ target_pos,
                const float* __restrict__ logsigma,
                const float* __restrict__ x_inits,
                const float* __restrict__ pw,
                const float* __restrict__ b1,
                const float* __restrict__ W2,
                const float* __restrict__ b2,
                float2* __restrict__ ws) {
    const int agent = blockIdx.x;
    const int tid  = threadIdx.x;   // 0..255
    const int wave = tid >> 6;      // 0..3
    const int lane = tid & 63;
    const int r    = wave >> 1;     // row-group: rows 64r+lane
    const int h    = wave & 1;      // age-half: ages 16h..16h+15
    const int row  = (r << 6) + lane;

    __shared__ float part1[2][32][64];          // h=1 -> h=0, 16-step delay
    __shared__ alignas(16) float2 pbf2[2][2];   // [parity][r] = (P0r, P1r)

    const float tx0 = uniformf(target_pos[0]), ty0 = uniformf(target_pos[1]);
    const float tx1 = uniformf(target_pos[2]), ty1 = uniformf(target_pos[3]);
    const float tx2 = uniformf(target_pos[4]), ty2 = uniformf(target_pos[5]);
    const float is0 = uniformf(1.0f / expf(logsigma[0]));
    const float is1 = uniformf(1.0f / expf(logsigma[1]));
    const float is2 = uniformf(1.0f / expf(logsigma[2]));

    // Paired weights for (row, ages 16h..16h+15): 16 (Wx,Wy) + 16 (Wz,Wc).
    v2f Wxy[16], Wzc[16];
    {
        const float* bxy = pw + row * 128 + 32 * h;
        const float* bzc = pw + row * 128 + 64 + 32 * h;
        #pragma unroll
        for (int i = 0; i < 16; ++i) {
            Wxy[i] = opaque_load8(bxy + 2 * i);
            Wzc[i] = opaque_load8(bzc + 2 * i);
        }
    }
    const float b1r = b1[row];                 // h=0 relu bias
    const float w2a = W2[row];                 // W2 row 0
    const float w2b = W2[HIDDEN + row];        // W2 row 1
    const float b2x = uniformf(b2[0]), b2y = uniformf(b2[1]);

    auto conc = [&](float px, float py) {
        float dx0 = px - tx0, dy0 = py - ty0;
        float dx1 = px - tx1, dy1 = py - ty1;
        float dx2 = px - tx2, dy2 = py - ty2;
        float cc  = is0 * __expf(-(dx0*dx0 + dy0*dy0) * is0);
        cc       += is1 * __expf(-(dx1*dx1 + dy1*dy1) * is1);
        cc       += is2 * __expf(-(dx2*dx2 + dy2*dy2) * is2);
        return cc;
    };

    float x  = uniformf(x_inits[3 * agent]);
    float y  = uniformf(x_inits[3 * agent + 1]);
    float th = uniformf(x_inits[3 * agent + 2]);
    float c  = conc(x, y);

    // Seed pending ring: history pre-filled with e(0).
    // R2[k] = sum_{m=k..15} pairs(m)·e(0); h_pre contribution = .lo + .hi.
    v2f R2[RING];
    #pragma unroll
    for (int i = 16; i < RING; ++i) R2[i] = (v2f){0.f, 0.f};
    {
        v2f exy = {x, y}, ezc = {th, c};
        v2f acc = {0.f, 0.f};
        #pragma unroll
        for (int k = 15; k >= 0; --k) {
            acc = Wxy[k] * exy + acc;
            acc = Wzc[k] * ezc + acc;
            R2[k] = acc;
        }
    }
    // h=1 partials for steps 0..15 = full 16-age e(0) sum.
    if (h == 1) {
        float s0 = R2[0].x + R2[0].y;
        #pragma unroll
        for (int s = 0; s < 16; ++s) part1[r][s][lane] = s0;
    }
    __syncthreads();

    float pl = part1[r][0][lane];   // prefetched h=1 partial for step 0
    float S_c = 0.f, S_u = 0.f;
    int t = 0;

    #pragma unroll 1
    for (int tt = 0; tt < T_STEPS / U; ++tt) {
        #pragma unroll
        for (int j = 0; j < U; ++j, ++t) {
            // ---- phase 1: h=0 completes h(t) + layer-2 DPP; h=1 ships ----
            if (h == 0) {
                float hv = fmaxf((R2[j].x + R2[j].y) + pl + b1r, 0.f);
                float s0 = wave_sum_dpp(w2a * hv);
                float s1 = wave_sum_dpp(w2b * hv);
                if (lane == 0) pbf2[t & 1][r] = make_float2(s0, s1);
            } else {
                part1[r][(t + 16) & 31][lane] = R2[j].x + R2[j].y;
            }
            __syncthreads();   // the ONE barrier per step

            // prefetch next step's h=1 partial (written >=15 barriers ago)
            pl = part1[r][(t + 1) & 31][lane];

            float4 pa = *(const float4*)&pbf2[t & 1][0];
            float P0 = pa.x + pa.z;
            float P1 = pa.y + pa.w;

            // ---- tail: redundant on all waves (per-lane state) ----
            float v  = tanh_fast(P0 + b2x);
            float wv = tanh_fast(P1 + b2y);
            S_u += v * v + wv * wv;

            float sn = __sinf(th), cs = __cosf(th);
            float dv = DT * v;
            x  = fmaf(dv, cs, x);
            y  = fmaf(dv, sn, y);
            th = fmaf(DT, wv, th);

            c = conc(x, y);
            S_c += c;

            // ---- push e(t+1): 32 v_pk_fma_f32 (double-rate fp32) ----
            {
                v2f exy = {x, y}, ezc = {th, c};
                #pragma unroll
                for (int k = 0; k < 16; ++k) {
                    R2[j+1+k] = Wxy[k] * exy + R2[j+1+k];
                    R2[j+1+k] = Wzc[k] * ezc + R2[j+1+k];
                }
            }
        }
        // ---- rotate pending ring by U ----
        #pragma unroll
        for (int i = 0; i < 16; ++i) R2[i] = R2[i + U];
        #pragma unroll
        for (int i = 16; i < RING; ++i) R2[i] = (v2f){0.f, 0.f};
    }

    if (tid == 0) ws[agent] = make_float2(S_c, S_u);
}

__global__ void reduce_kernel(const float2* __restrict__ ws,
                              float* __restrict__ out) {
    const int tid = threadIdx.x;  // 256 threads
    float sc = 0.f, su = 0.f;
    for (int i = tid; i < N_AGENTS; i += 256) {
        float2 v = ws[i];
        sc += v.x;
        su += v.y;
    }
    #pragma unroll
    for (int off = 32; off > 0; off >>= 1) {
        sc += __shfl_xor(sc, off);
        su += __shfl_xor(su, off);
    }
    __shared__ float2 partw[4];
    int wave = tid >> 6;
    if ((tid & 63) == 0) partw[wave] = make_float2(sc, su);
    __syncthreads();
    if (tid == 0) {
        float SC = partw[0].x + partw[1].x + partw[2].x + partw[3].x;
        float SU = partw[0].y + partw[1].y + partw[2].y + partw[3].y;
        const float invNT  = 1.0f / (float)(N_AGENTS * T_STEPS);
        const float invNT2 = 1.0f / (float)(N_AGENTS * T_STEPS * 2);
        out[0] = -SC * invNT + SU * invNT2;
    }
}

extern "C" void kernel_launch(void* const* d_in, const int* in_sizes, int n_in,
                              void* d_out, int out_size, void* d_ws, size_t ws_size,
                              hipStream_t stream) {
    const float* target_pos = (const float*)d_in[0];
    const float* logsigma   = (const float*)d_in[1];
    const float* x_inits    = (const float*)d_in[2];
    const float* W1         = (const float*)d_in[3];
    const float* b1         = (const float*)d_in[4];
    const float* W2         = (const float*)d_in[5];
    const float* b2         = (const float*)d_in[6];

    float*  pw   = (float*)d_ws;                          // 64 KB packed W1
    float2* sums = (float2*)((char*)d_ws + 64 * 1024);    // per-agent sums

    pack_kernel<<<HIDDEN, 32, 0, stream>>>(W1, pw);
    sim_kernel<<<N_AGENTS, 256, 0, stream>>>(target_pos, logsigma, x_inits,
                                             pw, b1, W2, b2, sums);
    reduce_kernel<<<1, 256, 0, stream>>>(sums, (float*)d_out);
}

// Round 15
// 734.402 us; speedup vs baseline: 7.4167x; 1.3517x over previous
//
#include <hip/hip_runtime.h>

#define T_STEPS 1000
#define DT 0.1f
#define HIDDEN 128
#define N_AGENTS 1024
#define U 2
#define RING (U + 16)   // pending-accumulator slots (v2f each, per row)

typedef float v2f __attribute__((ext_vector_type(2)));

// tanh(x) = 1 - 2/(exp(2x)+1); exact at +/-inf, ~1e-7 rel error.
__device__ __forceinline__ float tanh_fast(float x) {
    float e = __expf(2.0f * x);
    return 1.0f - 2.0f * __builtin_amdgcn_rcpf(e + 1.0f);
}

// Opaque 8B load (R13/R14-proven residency mechanism): asm output can't be
// remat'd/sunk, pair is even-aligned for v_pk_fma_f32.
__device__ __forceinline__ v2f opaque_load8(const float* p) {
    v2f v;
    asm volatile("global_load_dwordx2 %0, %1, off\n\ts_waitcnt vmcnt(0)"
                 : "=v"(v)
                 : "v"((unsigned long long)(uintptr_t)p)
                 : "memory");
    return v;
}

// Wave-uniform float -> SGPR.
__device__ __forceinline__ float uniformf(float v) {
    return __builtin_bit_cast(float,
        __builtin_amdgcn_readfirstlane(__builtin_bit_cast(int, v)));
}

// 64-lane sum on the VALU pipe via DPP row ops (R11/R13/R14-verified).
__device__ __forceinline__ float wave_sum_dpp(float x) {
    float t;
    #define DPPADD(ctrl, rmask)                                              \
        t = __builtin_bit_cast(float, __builtin_amdgcn_update_dpp(           \
                0, __builtin_bit_cast(int, x), ctrl, rmask, 0xf, false));    \
        x += t;
    DPPADD(0x111, 0xf)   // row_shr:1
    DPPADD(0x112, 0xf)   // row_shr:2
    DPPADD(0x114, 0xf)   // row_shr:4
    DPPADD(0x118, 0xf)   // row_shr:8
    DPPADD(0x142, 0xa)   // row_bcast15
    DPPADD(0x143, 0xc)   // row_bcast31; lane63 = full sum
    #undef DPPADD
    return __builtin_bit_cast(float,
        __builtin_amdgcn_readlane(__builtin_bit_cast(int, x), 63));
}

// Pre-pack W1 into component-paired layout (R14-verified):
//   pw[row*128 + 2a,2a+1]   = (Wx[a], Wy[a])    a = 0..31
//   pw[row*128 + 64+2a,+1]  = (Wz[a], Wc[a])
__global__ void pack_kernel(const float* __restrict__ W1,
                            float* __restrict__ pw) {
    const int row = blockIdx.x;     // 128
    const int a   = threadIdx.x;    // 32
    const float* rp = W1 + row * 128;
    float* out = pw + row * 128;
    out[2*a]          = rp[3*a];
    out[2*a + 1]      = rp[3*a + 1];
    out[64 + 2*a]     = rp[3*a + 2];
    out[64 + 2*a + 1] = rp[96 + a];
}

// TWO-WAVE AGENT (128 threads). Wave h owns ages 16h..16h+15 for TWO rows
// per lane (A=lane, B=lane+64): 128 weight floats = 64 pinned v2f pairs.
// vs R14's 4-wave agent this (1) halves tail redundancy (x4 -> x2),
// (2) gives exactly one grid pass (1024 x 2 waves = 2048 = 2/SIMD chip-
// wide, 4 blocks/CU), (3) keeps the proven single-barrier skeleton with
// DPP layer-2 + part1 prefetch. waves_per_eu(1,2): min=1 -> 512-reg
// budget -> spill is never forced (R7/R8/R12 all died by forced spill);
// natural usage ~230 regs -> 2 waves/SIMD.
__global__ __launch_bounds__(128)
__attribute__((amdgpu_waves_per_eu(1, 2)))
void sim_kernel(const float* __restrict__ target_pos,
                const float* __restrict__ logsigma,
                const float* __restrict__ x_inits,
                const float* __restrict__ pw,
                const float* __restrict__ b1,
                const float* __restrict__ W2,
                const float* __restrict__ b2,
                float2* __restrict__ ws) {
    const int agent = blockIdx.x;
    const int tid  = threadIdx.x;   // 0..127
    const int h    = tid >> 6;      // age-half: ages 16h..16h+15
    const int lane = tid & 63;
    const int rowA = lane;
    const int rowB = lane + 64;

    __shared__ float2 part1[32][64];           // h=1 -> h=0 (rows A,B packed)
    __shared__ alignas(16) float2 pbf[2];      // [parity] = (P0, P1)

    const float tx0 = uniformf(target_pos[0]), ty0 = uniformf(target_pos[1]);
    const float tx1 = uniformf(target_pos[2]), ty1 = uniformf(target_pos[3]);
    const float tx2 = uniformf(target_pos[4]), ty2 = uniformf(target_pos[5]);
    const float is0 = uniformf(1.0f / expf(logsigma[0]));
    const float is1 = uniformf(1.0f / expf(logsigma[1]));
    const float is2 = uniformf(1.0f / expf(logsigma[2]));

    // Paired weights for ages 16h..16h+15, rows A and B: 64 v2f pinned.
    v2f WxyA[16], WzcA[16], WxyB[16], WzcB[16];
    {
        const float* baseA = pw + rowA * 128;
        const float* baseB = pw + rowB * 128;
        #pragma unroll
        for (int i = 0; i < 16; ++i) {
            WxyA[i] = opaque_load8(baseA + 32 * h + 2 * i);
            WzcA[i] = opaque_load8(baseA + 64 + 32 * h + 2 * i);
            WxyB[i] = opaque_load8(baseB + 32 * h + 2 * i);
            WzcB[i] = opaque_load8(baseB + 64 + 32 * h + 2 * i);
        }
    }
    const float b1A = b1[rowA], b1B = b1[rowB];
    const float w20A = W2[rowA], w20B = W2[rowB];
    const float w21A = W2[HIDDEN + rowA], w21B = W2[HIDDEN + rowB];
    const float b2x = uniformf(b2[0]), b2y = uniformf(b2[1]);

    auto conc = [&](float px, float py) {
        float dx0 = px - tx0, dy0 = py - ty0;
        float dx1 = px - tx1, dy1 = py - ty1;
        float dx2 = px - tx2, dy2 = py - ty2;
        float cc  = is0 * __expf(-(dx0*dx0 + dy0*dy0) * is0);
        cc       += is1 * __expf(-(dx1*dx1 + dy1*dy1) * is1);
        cc       += is2 * __expf(-(dx2*dx2 + dy2*dy2) * is2);
        return cc;
    };

    float x  = uniformf(x_inits[3 * agent]);
    float y  = uniformf(x_inits[3 * agent + 1]);
    float th = uniformf(x_inits[3 * agent + 2]);
    float c  = conc(x, y);

    // Seed pending rings: history pre-filled with e(0).
    v2f RA[RING], RB[RING];
    #pragma unroll
    for (int i = 16; i < RING; ++i) { RA[i] = (v2f){0.f,0.f}; RB[i] = (v2f){0.f,0.f}; }
    {
        v2f exy = {x, y}, ezc = {th, c};
        v2f aA = {0.f, 0.f}, aB = {0.f, 0.f};
        #pragma unroll
        for (int k = 15; k >= 0; --k) {
            aA = WxyA[k] * exy + aA;  aA = WzcA[k] * ezc + aA;
            aB = WxyB[k] * exy + aB;  aB = WzcB[k] * ezc + aB;
            RA[k] = aA;  RB[k] = aB;
        }
    }
    // h=1 partials for steps 0..15 = full 16-age e(0) sums.
    if (h == 1) {
        float2 s0 = make_float2(RA[0].x + RA[0].y, RB[0].x + RB[0].y);
        #pragma unroll
        for (int s = 0; s < 16; ++s) part1[s][lane] = s0;
    }
    __syncthreads();

    float2 pl = part1[0][lane];   // prefetched h=1 partials for step 0
    float S_c = 0.f, S_u = 0.f;
    int t = 0;

    #pragma unroll 1
    for (int tt = 0; tt < T_STEPS / U; ++tt) {
        #pragma unroll
        for (int j = 0; j < U; ++j, ++t) {
            // ---- phase 1: h=0 completes h(t) + layer-2 DPP; h=1 ships ----
            if (h == 0) {
                float hA = fmaxf((RA[j].x + RA[j].y) + pl.x + b1A, 0.f);
                float hB = fmaxf((RB[j].x + RB[j].y) + pl.y + b1B, 0.f);
                float s0 = wave_sum_dpp(fmaf(w20A, hA, w20B * hB));
                float s1 = wave_sum_dpp(fmaf(w21A, hA, w21B * hB));
                if (lane == 0) pbf[t & 1] = make_float2(s0, s1);
            } else {
                part1[(t + 16) & 31][lane] =
                    make_float2(RA[j].x + RA[j].y, RB[j].x + RB[j].y);
            }
            __syncthreads();   // the ONE barrier per step

            // prefetch next step's h=1 partials (written >=15 barriers ago)
            pl = part1[(t + 1) & 31][lane];

            float2 pp = pbf[t & 1];
            float P0 = pp.x, P1 = pp.y;

            // ---- tail: redundant on BOTH waves (per-lane state) ----
            float v  = tanh_fast(P0 + b2x);
            float wv = tanh_fast(P1 + b2y);
            S_u += v * v + wv * wv;

            float sn = __sinf(th), cs = __cosf(th);
            float dv = DT * v;
            x  = fmaf(dv, cs, x);
            y  = fmaf(dv, sn, y);
            th = fmaf(DT, wv, th);

            c = conc(x, y);
            S_c += c;

            // ---- push e(t+1): 64 v_pk_fma_f32 (2 rows x 16 ages x 2) ----
            {
                v2f exy = {x, y}, ezc = {th, c};
                #pragma unroll
                for (int k = 0; k < 16; ++k) {
                    RA[j+1+k] = WxyA[k] * exy + RA[j+1+k];
                    RA[j+1+k] = WzcA[k] * ezc + RA[j+1+k];
                    RB[j+1+k] = WxyB[k] * exy + RB[j+1+k];
                    RB[j+1+k] = WzcB[k] * ezc + RB[j+1+k];
                }
            }
        }
        // ---- rotate pending rings by U ----
        #pragma unroll
        for (int i = 0; i < 16; ++i) { RA[i] = RA[i + U]; RB[i] = RB[i + U]; }
        #pragma unroll
        for (int i = 16; i < RING; ++i) { RA[i] = (v2f){0.f,0.f}; RB[i] = (v2f){0.f,0.f}; }
    }

    if (tid == 0) ws[agent] = make_float2(S_c, S_u);
}

__global__ void reduce_kernel(const float2* __restrict__ ws,
                              float* __restrict__ out) {
    const int tid = threadIdx.x;  // 256 threads
    float sc = 0.f, su = 0.f;
    for (int i = tid; i < N_AGENTS; i += 256) {
        float2 v = ws[i];
        sc += v.x;
        su += v.y;
    }
    #pragma unroll
    for (int off = 32; off > 0; off >>= 1) {
        sc += __shfl_xor(sc, off);
        su += __shfl_xor(su, off);
    }
    __shared__ float2 partw[4];
    int wave = tid >> 6;
    if ((tid & 63) == 0) partw[wave] = make_float2(sc, su);
    __syncthreads();
    if (tid == 0) {
        float SC = partw[0].x + partw[1].x + partw[2].x + partw[3].x;
        float SU = partw[0].y + partw[1].y + partw[2].y + partw[3].y;
        const float invNT  = 1.0f / (float)(N_AGENTS * T_STEPS);
        const float invNT2 = 1.0f / (float)(N_AGENTS * T_STEPS * 2);
        out[0] = -SC * invNT + SU * invNT2;
    }
}

extern "C" void kernel_launch(void* const* d_in, const int* in_sizes, int n_in,
                              void* d_out, int out_size, void* d_ws, size_t ws_size,
                              hipStream_t stream) {
    const float* target_pos = (const float*)d_in[0];
    const float* logsigma   = (const float*)d_in[1];
    const float* x_inits    = (const float*)d_in[2];
    const float* W1         = (const float*)d_in[3];
    const float* b1         = (const float*)d_in[4];
    const float* W2         = (const float*)d_in[5];
    const float* b2         = (const float*)d_in[6];

    float*  pw   = (float*)d_ws;                          // 64 KB packed W1
    float2* sums = (float2*)((char*)d_ws + 64 * 1024);    // per-agent sums

    pack_kernel<<<HIDDEN, 32, 0, stream>>>(W1, pw);
    sim_kernel<<<N_AGENTS, 128, 0, stream>>>(target_pos, logsigma, x_inits,
                                             pw, b1, W2, b2, sums);
    reduce_kernel<<<1, 256, 0, stream>>>(sums, (float*)d_out);
}

// Round 16
// 661.129 us; speedup vs baseline: 8.2387x; 1.1108x over previous
//
#include <hip/hip_runtime.h>

#define T_STEPS 1000
#define DT 0.1f
#define HIDDEN 128
#define N_AGENTS 1024

typedef float v2f __attribute__((ext_vector_type(2)));

// tanh(x) = 1 - 2/(exp(2x)+1); exact at +/-inf, ~1e-7 rel error.
__device__ __forceinline__ float tanh_fast(float x) {
    float e = __expf(2.0f * x);
    return 1.0f - 2.0f * __builtin_amdgcn_rcpf(e + 1.0f);
}

// Opaque 8B load (R13-R15 proven residency mechanism).
__device__ __forceinline__ v2f opaque_load8(const float* p) {
    v2f v;
    asm volatile("global_load_dwordx2 %0, %1, off\n\ts_waitcnt vmcnt(0)"
                 : "=v"(v)
                 : "v"((unsigned long long)(uintptr_t)p)
                 : "memory");
    return v;
}

__device__ __forceinline__ float uniformf(float v) {
    return __builtin_bit_cast(float,
        __builtin_amdgcn_readfirstlane(__builtin_bit_cast(int, v)));
}

// 64-lane sum on the VALU pipe via DPP row ops (R11-R15 verified).
__device__ __forceinline__ float wave_sum_dpp(float x) {
    float t;
    #define DPPADD(ctrl, rmask)                                              \
        t = __builtin_bit_cast(float, __builtin_amdgcn_update_dpp(           \
                0, __builtin_bit_cast(int, x), ctrl, rmask, 0xf, false));    \
        x += t;
    DPPADD(0x111, 0xf)
    DPPADD(0x112, 0xf)
    DPPADD(0x114, 0xf)
    DPPADD(0x118, 0xf)
    DPPADD(0x142, 0xa)
    DPPADD(0x143, 0xc)
    #undef DPPADD
    return __builtin_bit_cast(float,
        __builtin_amdgcn_readlane(__builtin_bit_cast(int, x), 63));
}

// Pre-pack W1 into component-paired layout (R14/R15-verified).
__global__ void pack_kernel(const float* __restrict__ W1,
                            float* __restrict__ pw) {
    const int row = blockIdx.x;     // 128
    const int a   = threadIdx.x;    // 32
    const float* rp = W1 + row * 128;
    float* out = pw + row * 128;
    out[2*a]          = rp[3*a];
    out[2*a + 1]      = rp[3*a + 1];
    out[64 + 2*a]     = rp[3*a + 2];
    out[64 + 2*a + 1] = rp[96 + a];
}

// ROLE-ASYMMETRIC 2-WAVE AGENT (128 threads), mod-16 register ring.
//  h=0 (consumer): owns ages 0..15 of rows (lane, lane+64). Completes h(t),
//    DPP layer-2 (result broadcast in-wave -> NO pbf, NO barrier before the
//    tail), computes the tail ONCE, publishes state e(t+1) to e4buf[(t+1)&3],
//    pushes with current state.
//  h=1 (producer): owns ages 16..31. Reads state e(t-1) from e4buf[(t-1)&3]
//    (written at window t-2 -> 2-barrier separation), pushes 1-step delayed
//    (partial for s still complete at s-15), ships partial for s=t+15 to
//    part1[(t+15)&31] (consumed 14 barriers later as h=0's prefetched pl).
// ONE barrier per window for both roles (equal counts; R12-proven pattern).
// Ring: 16 v2f slots/row, slot = s mod 16, k=15 ASSIGNS (fresh slot) ->
// no rotate, no zero-fill, all indices compile-time via 16-step unroll.
__global__ __launch_bounds__(128)
__attribute__((amdgpu_waves_per_eu(1, 2)))
void sim_kernel(const float* __restrict__ target_pos,
                const float* __restrict__ logsigma,
                const float* __restrict__ x_inits,
                const float* __restrict__ pw,
                const float* __restrict__ b1,
                const float* __restrict__ W2,
                const float* __restrict__ b2,
                float2* __restrict__ ws) {
    const int agent = blockIdx.x;
    const int tid  = threadIdx.x;   // 0..127
    const int h    = tid >> 6;      // 0 = consumer, 1 = producer
    const int lane = tid & 63;
    const int rowA = lane;
    const int rowB = lane + 64;

    __shared__ float2 part1[32][64];        // h=1 -> h=0 partial ring
    __shared__ float4 e4buf[4];             // state ring, 4-deep

    const float tx0 = uniformf(target_pos[0]), ty0 = uniformf(target_pos[1]);
    const float tx1 = uniformf(target_pos[2]), ty1 = uniformf(target_pos[3]);
    const float tx2 = uniformf(target_pos[4]), ty2 = uniformf(target_pos[5]);
    const float is0 = uniformf(1.0f / expf(logsigma[0]));
    const float is1 = uniformf(1.0f / expf(logsigma[1]));
    const float is2 = uniformf(1.0f / expf(logsigma[2]));

    // Paired weights for ages 16h..16h+15, rows A and B: 64 v2f pinned.
    v2f WxyA[16], WzcA[16], WxyB[16], WzcB[16];
    {
        const float* baseA = pw + rowA * 128;
        const float* baseB = pw + rowB * 128;
        #pragma unroll
        for (int i = 0; i < 16; ++i) {
            WxyA[i] = opaque_load8(baseA + 32 * h + 2 * i);
            WzcA[i] = opaque_load8(baseA + 64 + 32 * h + 2 * i);
            WxyB[i] = opaque_load8(baseB + 32 * h + 2 * i);
            WzcB[i] = opaque_load8(baseB + 64 + 32 * h + 2 * i);
        }
    }
    const float b1A = b1[rowA], b1B = b1[rowB];
    const float w20A = W2[rowA], w20B = W2[rowB];
    const float w21A = W2[HIDDEN + rowA], w21B = W2[HIDDEN + rowB];
    const float b2x = uniformf(b2[0]), b2y = uniformf(b2[1]);

    auto conc = [&](float px, float py) {
        float dx0 = px - tx0, dy0 = py - ty0;
        float dx1 = px - tx1, dy1 = py - ty1;
        float dx2 = px - tx2, dy2 = py - ty2;
        float cc  = is0 * __expf(-(dx0*dx0 + dy0*dy0) * is0);
        cc       += is1 * __expf(-(dx1*dx1 + dy1*dy1) * is1);
        cc       += is2 * __expf(-(dx2*dx2 + dy2*dy2) * is2);
        return cc;
    };

    float x  = uniformf(x_inits[3 * agent]);
    float y  = uniformf(x_inits[3 * agent + 1]);
    float th = uniformf(x_inits[3 * agent + 2]);
    float c  = conc(x, y);

    v2f RA[16], RB[16];
    {
        v2f exy0 = {x, y}, ezc0 = {th, c};
        if (h == 0) {
            // seed slot s (s=0..15): sum_{k=s..15} W[k]·e(0)
            v2f aA = {0.f,0.f}, aB = {0.f,0.f};
            #pragma unroll
            for (int k = 15; k >= 0; --k) {
                aA = WxyA[k]*exy0 + aA;  aA = WzcA[k]*ezc0 + aA;
                aB = WxyB[k]*exy0 + aB;  aB = WzcB[k]*ezc0 + aB;
                RA[k] = aA;  RB[k] = aB;
            }
            if (lane == 0) {
                float4 e0 = make_float4(x, y, th, c);
                e4buf[3] = e0;   // read by h=1 at t=0 (e(-1)=e(0))
                e4buf[0] = e0;   // read by h=1 at t=1 (e(0))
            }
        } else {
            // seed: slot m=15: k>=1 ; m=0..13: k>=m+2 ; m=14: 0
            v2f aA = {0.f,0.f}, aB = {0.f,0.f};
            RA[14] = (v2f){0.f,0.f};  RB[14] = (v2f){0.f,0.f};
            #pragma unroll
            for (int k = 15; k >= 2; --k) {
                aA = WxyA[k]*exy0 + aA;  aA = WzcA[k]*ezc0 + aA;
                aB = WxyB[k]*exy0 + aB;  aB = WzcB[k]*ezc0 + aB;
                RA[k-2] = aA;  RB[k-2] = aB;
            }
            aA = WxyA[1]*exy0 + aA;  aA = WzcA[1]*ezc0 + aA;
            aB = WxyB[1]*exy0 + aB;  aB = WzcB[1]*ezc0 + aB;
            RA[15] = aA;  RB[15] = aB;
            // prefill part1 for steps 0..15 with full 16-age e(0) sums
            v2f fA = WxyA[0]*exy0 + aA;  fA = WzcA[0]*ezc0 + fA;
            v2f fB = WxyB[0]*exy0 + aB;  fB = WzcB[0]*ezc0 + fB;
            float2 full = make_float2(fA.x + fA.y, fB.x + fB.y);
            #pragma unroll
            for (int s = 0; s < 16; ++s) part1[s][lane] = full;
        }
    }
    __syncthreads();

    float S_c = 0.f, S_u = 0.f;

    if (h == 0) {
        float2 pl = part1[0][lane];   // partial_1 for step 0
        auto h0_step = [&](int t, int j) {
            __syncthreads();
            // consume slot j (= t mod 16)
            float hA = fmaxf((RA[j].x + RA[j].y) + pl.x + b1A, 0.f);
            float hB = fmaxf((RB[j].x + RB[j].y) + pl.y + b1B, 0.f);
            float s0 = wave_sum_dpp(fmaf(w20A, hA, w20B * hB));
            float s1 = wave_sum_dpp(fmaf(w21A, hA, w21B * hB));
            float v  = tanh_fast(s0 + b2x);
            float wv = tanh_fast(s1 + b2y);
            S_u += v * v + wv * wv;
            float sn = __sinf(th), cs = __cosf(th);
            float dv = DT * v;
            x  = fmaf(dv, cs, x);
            y  = fmaf(dv, sn, y);
            th = fmaf(DT, wv, th);
            c  = conc(x, y);
            S_c += c;
            if (lane == 0) e4buf[(t + 1) & 3] = make_float4(x, y, th, c);
            v2f exy = {x, y}, ezc = {th, c};
            // push e(t+1): k=15 assigns slot j; k=0..14 accumulate
            RA[j] = WxyA[15] * exy;  RA[j] = WzcA[15] * ezc + RA[j];
            RB[j] = WxyB[15] * exy;  RB[j] = WzcB[15] * ezc + RB[j];
            #pragma unroll
            for (int k = 0; k < 15; ++k) {
                const int m = (j + 1 + k) & 15;
                RA[m] = WxyA[k] * exy + RA[m];  RA[m] = WzcA[k] * ezc + RA[m];
                RB[m] = WxyB[k] * exy + RB[m];  RB[m] = WzcB[k] * ezc + RB[m];
            }
            pl = part1[(t + 1) & 31][lane];   // prefetch next partial
        };
        #pragma unroll 1
        for (int tt = 0; tt < 62; ++tt) {
            const int tb = tt * 16;
            #pragma unroll
            for (int j = 0; j < 16; ++j) h0_step(tb + j, j);
        }
        #pragma unroll
        for (int j = 0; j < 8; ++j) h0_step(992 + j, j);

        if (lane == 0) ws[agent] = make_float2(S_c, S_u);
    } else {
        auto h1_step = [&](int t, int j) {
            __syncthreads();
            float4 e = e4buf[(t - 1) & 3];    // state e(t-1), 2 barriers old
            v2f exy = {e.x, e.y}, ezc = {e.z, e.w};
            // push e(t-1): k=15 assigns slot (j+14); k=0..14 accumulate
            {
                const int m = (j + 14) & 15;
                RA[m] = WxyA[15] * exy;  RA[m] = WzcA[15] * ezc + RA[m];
                RB[m] = WxyB[15] * exy;  RB[m] = WzcB[15] * ezc + RB[m];
            }
            #pragma unroll
            for (int k = 0; k < 15; ++k) {
                const int m = (j + 15 + k) & 15;
                RA[m] = WxyA[k] * exy + RA[m];  RA[m] = WzcA[k] * ezc + RA[m];
                RB[m] = WxyB[k] * exy + RB[m];  RB[m] = WzcB[k] * ezc + RB[m];
            }
            // ship partial for s = t+15 (slot j+15, just completed by k=0)
            {
                const int m = (j + 15) & 15;
                part1[(t + 15) & 31][lane] =
                    make_float2(RA[m].x + RA[m].y, RB[m].x + RB[m].y);
            }
        };
        #pragma unroll 1
        for (int tt = 0; tt < 62; ++tt) {
            const int tb = tt * 16;
            #pragma unroll
            for (int j = 0; j < 16; ++j) h1_step(tb + j, j);
        }
        #pragma unroll
        for (int j = 0; j < 8; ++j) h1_step(992 + j, j);
    }
}

__global__ void reduce_kernel(const float2* __restrict__ ws,
                              float* __restrict__ out) {
    const int tid = threadIdx.x;  // 256 threads
    float sc = 0.f, su = 0.f;
    for (int i = tid; i < N_AGENTS; i += 256) {
        float2 v = ws[i];
        sc += v.x;
        su += v.y;
    }
    #pragma unroll
    for (int off = 32; off > 0; off >>= 1) {
        sc += __shfl_xor(sc, off);
        su += __shfl_xor(su, off);
    }
    __shared__ float2 partw[4];
    int wave = tid >> 6;
    if ((tid & 63) == 0) partw[wave] = make_float2(sc, su);
    __syncthreads();
    if (tid == 0) {
        float SC = partw[0].x + partw[1].x + partw[2].x + partw[3].x;
        float SU = partw[0].y + partw[1].y + partw[2].y + partw[3].y;
        const float invNT  = 1.0f / (float)(N_AGENTS * T_STEPS);
        const float invNT2 = 1.0f / (float)(N_AGENTS * T_STEPS * 2);
        out[0] = -SC * invNT + SU * invNT2;
    }
}

extern "C" void kernel_launch(void* const* d_in, const int* in_sizes, int n_in,
                              void* d_out, int out_size, void* d_ws, size_t ws_size,
                              hipStream_t stream) {
    const float* target_pos = (const float*)d_in[0];
    const float* logsigma   = (const float*)d_in[1];
    const float* x_inits    = (const float*)d_in[2];
    const float* W1         = (const float*)d_in[3];
    const float* b1         = (const float*)d_in[4];
    const float* W2         = (const float*)d_in[5];
    const float* b2         = (const float*)d_in[6];

    float*  pw   = (float*)d_ws;                          // 64 KB packed W1
    float2* sums = (float2*)((char*)d_ws + 64 * 1024);    // per-agent sums

    pack_kernel<<<HIDDEN, 32, 0, stream>>>(W1, pw);
    sim_kernel<<<N_AGENTS, 128, 0, stream>>>(target_pos, logsigma, x_inits,
                                             pw, b1, W2, b2, sums);
    reduce_kernel<<<1, 256, 0, stream>>>(sums, (float*)d_out);
}